// Round 10
// baseline (371.600 us; speedup 1.0000x reference)
//
#include <hip/hip_runtime.h>
#include <hip/hip_bf16.h>
#include <stdint.h>

// ---------------------------------------------------------------------------
// GCN forward: 3 layers of  out = Ahat * (X @ W) + b, relu between layers.
// Factored normalization: out[d] = dinv[d]*( sum_{s in in(d)} H'[s] + H'[d] ) + b
// where H'[i] = bf16( dinv[i] * (A@W)[i] ).
// Activations Y between layers stored BF16.
// GEMM: MFMA bf16; W hi/lo split; layer-0 A split via TRUNCATION (hi=trunc16,
// rem exact, lo=trunc16(rem)) -> ~4 VALU/elem staging.
// CSR build: two-level counting sort, zero global atomics; bindeg+csr FUSED
// (one pass computes row_ptr/dinv, second pass fills col_idx from LDS cursors).
// Aggregation: wave-per-node quarter/octal-wave u128 gather, 24-bit byte
// offsets (saddr-form loads), zero-row padding, shfl_xor combine.
// ---------------------------------------------------------------------------

typedef __attribute__((ext_vector_type(8))) short bf16x8;
typedef __attribute__((ext_vector_type(4))) float f32x4;

__device__ __forceinline__ float bflo(uint32_t u) { return __uint_as_float(u << 16); }
__device__ __forceinline__ float bfhi(uint32_t u) { return __uint_as_float(u & 0xffff0000u); }
__device__ __forceinline__ unsigned short f2bf(float f) {
    uint32_t x = __float_as_uint(f);
    return (unsigned short)((x + 0x7fffu + ((x >> 16) & 1u)) >> 16);
}

#define CE   4096   // edges per chunk
#define BINW 256    // nodes per bin

// per-chunk per-bin histogram (LDS only; fully overwrites cnt -> no memset)
__global__ __launch_bounds__(256) void k_binhist(const int* __restrict__ dst,
                                                 int* __restrict__ cnt,
                                                 int NBIN, int E) {
    extern __shared__ int h[];
    int c = blockIdx.x, base = c * CE;
    for (int i = threadIdx.x; i < NBIN; i += 256) h[i] = 0;
    __syncthreads();
    for (int i = 0; i < CE; i += 256) {
        int e = base + i + threadIdx.x;
        if (e < E) atomicAdd(&h[dst[e] >> 8], 1);
    }
    __syncthreads();
    for (int i = threadIdx.x; i < NBIN; i += 256) cnt[c * NBIN + i] = h[i];
}

// per-bin exclusive scan over chunks: off_cb[c][b], tot[b]
__global__ __launch_bounds__(256) void k_colscan(const int* __restrict__ cnt,
                                                 int* __restrict__ off_cb,
                                                 int* __restrict__ tot,
                                                 int NBIN, int NCHUNK) {
    __shared__ int part[256];
    int b = blockIdx.x, t = threadIdx.x;
    int K = (NCHUNK + 255) >> 8;
    int c0 = t * K;
    int vals[16];                       // K <= 16 (E <= 16.7M)
    int s = 0;
    for (int k = 0; k < K; ++k) {
        int c = c0 + k;
        int v = (c < NCHUNK) ? cnt[c * NBIN + b] : 0;
        vals[k] = s;                    // thread-local exclusive prefix
        s += v;
    }
    part[t] = s;
    __syncthreads();
    for (int off = 1; off < 256; off <<= 1) {
        int x = (t >= off) ? part[t - off] : 0;
        __syncthreads();
        part[t] += x;
        __syncthreads();
    }
    int run = (t == 0) ? 0 : part[t - 1];
    for (int k = 0; k < K; ++k) {
        int c = c0 + k;
        if (c < NCHUNK) off_cb[c * NBIN + b] = run + vals[k];
    }
    if (t == 255) tot[b] = part[255];
}

// scan bin totals -> bin_off; also zero agg dummy row, row_ptr[N]=E
__global__ __launch_bounds__(512) void k_binoff(const int* __restrict__ tot,
                                                int* __restrict__ bin_off,
                                                int* __restrict__ row_ptr,
                                                unsigned short* __restrict__ hzero,
                                                int NBIN, int N, int E) {
    __shared__ int part[512];
    int t = threadIdx.x;
    int v = (t < NBIN) ? tot[t] : 0;
    part[t] = v;
    __syncthreads();
    for (int off = 1; off < 512; off <<= 1) {
        int x = (t >= off) ? part[t - off] : 0;
        __syncthreads();
        part[t] += x;
        __syncthreads();
    }
    if (t < NBIN) bin_off[t] = part[t] - v;     // exclusive
    if (t == 0) { bin_off[NBIN] = E; row_ptr[N] = E; }
    if (t < 16) { uint4 z; z.x = z.y = z.z = z.w = 0; ((uint4*)hzero)[t] = z; }
}

// scatter edges into bin-sorted order at precomputed slots (LDS cursors only).
// pack = (d & 255) << 24 | src   (src < 2^24)
__global__ __launch_bounds__(256) void k_binscatter(const int* __restrict__ src,
                                                    const int* __restrict__ dst,
                                                    const int* __restrict__ off_cb,
                                                    const int* __restrict__ bin_off,
                                                    unsigned int* __restrict__ bpack,
                                                    int NBIN, int E) {
    extern __shared__ int lcur[];
    int c = blockIdx.x, base = c * CE;
    for (int i = threadIdx.x; i < NBIN; i += 256)
        lcur[i] = off_cb[c * NBIN + i] + bin_off[i];
    __syncthreads();
    for (int i = 0; i < CE; i += 256) {
        int e = base + i + threadIdx.x;
        if (e < E) {
            int d = dst[e], s = src[e];
            int pos = atomicAdd(&lcur[d >> 8], 1);
            bpack[pos] = (unsigned)s | ((unsigned)(d & 255) << 24);
        }
    }
}

// FUSED block-per-bin: pass 1 = LDS deg hist + scan -> row_ptr, dinv;
// pass 2 = CSR fill from LDS cursors (bpack span is L2-hot on 2nd pass).
__global__ __launch_bounds__(256) void k_bincsr(const unsigned int* __restrict__ bpack,
                                                const int* __restrict__ bin_off,
                                                int* __restrict__ row_ptr,
                                                float* __restrict__ dinv,
                                                int* __restrict__ col_idx, int N) {
    __shared__ int h[256];
    __shared__ int part[256];
    __shared__ int lcur[256];
    int b = blockIdx.x, t = threadIdx.x;
    int lo = b * BINW;
    h[t] = 0;
    __syncthreads();
    int s0 = bin_off[b], s1 = bin_off[b + 1];
    for (int i = s0 + t; i < s1; i += 256)
        atomicAdd(&h[bpack[i] >> 24], 1);
    __syncthreads();
    int dg = h[t];
    part[t] = dg;
    __syncthreads();
    for (int off = 1; off < 256; off <<= 1) {
        int x = (t >= off) ? part[t - off] : 0;
        __syncthreads();
        part[t] += x;
        __syncthreads();
    }
    int rstart = s0 + part[t] - dg;     // bin start + in-bin exclusive prefix
    lcur[t] = rstart;
    if (lo + t < N) {
        row_ptr[lo + t] = rstart;
        dinv[lo + t] = rsqrtf((float)(dg + 1));  // +1 self-loop
    }
    __syncthreads();
    for (int i = s0 + t; i < s1; i += 256) {
        unsigned pk = bpack[i];
        int pos = atomicAdd(&lcur[pk >> 24], 1);
        col_idx[pos] = (int)(pk & 0xFFFFFFu);
    }
}

// W [K][M] f32 -> Wt_hi[c][k], Wt_lo[c][k] bf16 (transposed, hi plane then lo)
__global__ __launch_bounds__(256) void k_prepw(const float* __restrict__ W0,
                                               const float* __restrict__ W1,
                                               const float* __restrict__ W2,
                                               unsigned short* __restrict__ wt0,
                                               unsigned short* __restrict__ wt1,
                                               unsigned short* __restrict__ wt2) {
    int id = blockIdx.x * 256 + threadIdx.x;
    const float* Wsrc;
    unsigned short* dst;
    int t, M, plane;
    if (id < 16384)      { t = id;         Wsrc = W0; dst = wt0; M = 128; plane = 16384; }
    else if (id < 32768) { t = id - 16384; Wsrc = W1; dst = wt1; M = 128; plane = 16384; }
    else if (id < 40960) { t = id - 32768; Wsrc = W2; dst = wt2; M = 64;  plane = 8192;  }
    else return;
    int k = (M == 128) ? (t >> 7) : (t >> 6);
    int c = (M == 128) ? (t & 127) : (t & 63);
    float v = Wsrc[k * M + c];
    unsigned short hi = f2bf(v);
    float lov = v - bflo((uint32_t)hi);
    dst[c * 128 + k]         = hi;
    dst[plane + c * 128 + k] = f2bf(lov);
}

// H[r,:] = bf16( dinv[r] * (A[r,:] @ W) ) via MFMA.
// BF16A=false: A f32 [N,128], TRUNCATION hi/lo split, 3 MFMA per tile.
// BF16A=true : A bf16 [N,128], single plane, 2 MFMA per tile.
// W always hi/lo bf16 [NCOL][128] x2. Tile 128 rows x NCOL, K-tiled by 64.
template <int NCOL, bool BF16A>
__global__ __launch_bounds__(256) void k_gemm_mfma(
    const void* __restrict__ Av, const unsigned short* __restrict__ Wt,
    const float* __restrict__ dinv, unsigned short* __restrict__ H, int N) {
    constexpr int K = 128, KT = 64;
    constexpr int A_SH = 128 * KT;        // shorts per A plane
    constexpr int APL = BF16A ? 1 : 2;
    constexpr int W_PLANE = NCOL * KT;
    __shared__ __align__(16) unsigned short sm[APL * A_SH + 2 * W_PLANE];
    unsigned short* Ah  = sm;
    unsigned short* Al  = sm + A_SH;                 // only used if !BF16A
    unsigned short* Whp = sm + APL * A_SH;
    unsigned short* Wlp = sm + APL * A_SH + W_PLANE;

    const int tid = threadIdx.x;
    const long r0 = (long)blockIdx.x * 128;
    const int w = tid >> 6, l = tid & 63;
    const int lr = l & 15, lk = l >> 4;
    constexpr int WR = (NCOL == 128) ? 4 : 2;          // 16-row frags per wave
    const int wrow = (NCOL == 128) ? (w >> 1) * 64 : w * 32;
    const int wcol = (NCOL == 128) ? (w & 1) * 64 : 0;

    f32x4 acc[WR][4];
#pragma unroll
    for (int i = 0; i < WR; ++i)
#pragma unroll
        for (int j = 0; j < 4; ++j) acc[i][j] = (f32x4){0.f, 0.f, 0.f, 0.f};

    for (int kt = 0; kt < 2; ++kt) {
        if (kt) __syncthreads();           // previous compute done
        // ---- stage A tile: 128 rows x 64 k, swizzled ----
#pragma unroll
        for (int it = 0; it < 4; ++it) {
            int id = it * 256 + tid;
            int r = id >> 3, kc = id & 7;   // 8 chunks of 8 elems per row
            long gr = r0 + r;
            if (gr >= N) gr = N - 1;
            int boff = r * 128 + ((kc * 16) ^ ((r & 7) << 4));
            if constexpr (BF16A) {
                const unsigned short* ap =
                    (const unsigned short*)Av + gr * K + kt * KT + kc * 8;
                *(bf16x8*)((char*)Ah + boff) = *(const bf16x8*)ap;
            } else {
                const float* ap = (const float*)Av + gr * K + kt * KT + kc * 8;
                float4 v0 = *(const float4*)ap;
                float4 v1 = *(const float4*)(ap + 4);
                float vv[8] = {v0.x, v0.y, v0.z, v0.w, v1.x, v1.y, v1.z, v1.w};
                union { unsigned short u[8]; bf16x8 v; } ph, pl;
#pragma unroll
                for (int j = 0; j < 8; ++j) {
                    // truncation split: hi = top16(v); rem = v - hi (exact);
                    // lo = top16(rem). err ~2^-16 rel, invisible vs bf16 store.
                    uint32_t vb = __float_as_uint(vv[j]);
                    ph.u[j] = (unsigned short)(vb >> 16);
                    float rem = vv[j] - bfhi(vb);
                    pl.u[j] = (unsigned short)(__float_as_uint(rem) >> 16);
                }
                *(bf16x8*)((char*)Ah + boff) = ph.v;
                *(bf16x8*)((char*)Al + boff) = pl.v;
            }
        }
        // ---- stage W tile: NCOL rows x 64 k, hi+lo, swizzled ----
#pragma unroll
        for (int it = 0; it < NCOL / 32; ++it) {
            int id = it * 256 + tid;
            int c = id >> 3, kc = id & 7;
            const unsigned short* wp = &Wt[c * K + kt * KT + kc * 8];
            bf16x8 vh = *(const bf16x8*)wp;
            bf16x8 vl = *(const bf16x8*)(wp + NCOL * K);
            int boff = c * 128 + ((kc * 16) ^ ((c & 7) << 4));
            *(bf16x8*)((char*)Whp + boff) = vh;
            *(bf16x8*)((char*)Wlp + boff) = vl;
        }
        __syncthreads();
        // ---- compute: 2 k-steps of 32 ----
#pragma unroll
        for (int ks = 0; ks < 2; ++ks) {
            int kb = ks * 64 + lk * 16;
            bf16x8 bh[4], bl[4];
#pragma unroll
            for (int cf = 0; cf < 4; ++cf) {
                int c = wcol + cf * 16 + lr;
                int off = c * 128 + (kb ^ ((c & 7) << 4));
                bh[cf] = *(bf16x8*)((char*)Whp + off);
                bl[cf] = *(bf16x8*)((char*)Wlp + off);
            }
#pragma unroll
            for (int rf = 0; rf < WR; ++rf) {
                int r = wrow + rf * 16 + lr;
                int off = r * 128 + (kb ^ ((r & 7) << 4));
                bf16x8 ah = *(bf16x8*)((char*)Ah + off);
                if constexpr (BF16A) {
#pragma unroll
                    for (int cf = 0; cf < 4; ++cf) {
                        acc[rf][cf] = __builtin_amdgcn_mfma_f32_16x16x32_bf16(ah, bh[cf], acc[rf][cf], 0, 0, 0);
                        acc[rf][cf] = __builtin_amdgcn_mfma_f32_16x16x32_bf16(ah, bl[cf], acc[rf][cf], 0, 0, 0);
                    }
                } else {
                    bf16x8 al = *(bf16x8*)((char*)Al + off);
#pragma unroll
                    for (int cf = 0; cf < 4; ++cf) {
                        acc[rf][cf] = __builtin_amdgcn_mfma_f32_16x16x32_bf16(ah, bh[cf], acc[rf][cf], 0, 0, 0);
                        acc[rf][cf] = __builtin_amdgcn_mfma_f32_16x16x32_bf16(al, bh[cf], acc[rf][cf], 0, 0, 0);
                        acc[rf][cf] = __builtin_amdgcn_mfma_f32_16x16x32_bf16(ah, bl[cf], acc[rf][cf], 0, 0, 0);
                    }
                }
            }
        }
    }
    // ---- epilogue: C frag (col=lane&15, row=(lane>>4)*4+reg), scale, bf16 ----
#pragma unroll
    for (int rf = 0; rf < WR; ++rf) {
        long rb = r0 + wrow + rf * 16 + lk * 4;
#pragma unroll
        for (int reg = 0; reg < 4; ++reg) {
            long r = rb + reg;
            if (r < N) {
                float dv = dinv[r];
#pragma unroll
                for (int cf = 0; cf < 4; ++cf) {
                    int c = wcol + cf * 16 + lr;
                    H[r * NCOL + c] = f2bf(dv * acc[rf][cf][reg]);
                }
            }
        }
    }
}

// One wave per node. Row of F bf16 = F/8 lanes x 16B -> EPW = 64/(F/8) edges
// per VMEM instruction (4 for F=128, 8 for F=64). 24-bit byte offsets so the
// compiler emits saddr-form loads (no 64-bit mul chain). Slice partials
// combine via shfl_xor; tail edges padded with DUMMY -> zero row.
template <int F, bool RELU, bool OUTBF16>
__global__ __launch_bounds__(256) void k_agg(const unsigned short* __restrict__ H,
                                             const int* __restrict__ row_ptr,
                                             const int* __restrict__ col_idx,
                                             const float* __restrict__ dinv,
                                             const float* __restrict__ bias,
                                             void* __restrict__ Yv, int N) {
    constexpr int LPR = F / 8;          // lanes per row (16 or 8)
    constexpr int EPW = 64 / LPR;       // edges per wave instr (4 or 8)
    constexpr int SH  = (F == 128) ? 8 : 7;   // log2(row bytes)
    int lane = threadIdx.x & 63;
    int node = blockIdx.x * 4 + (threadIdx.x >> 6);
    if (node >= N) return;
    const int q  = lane / LPR;          // edge slot within group
    const unsigned qb = (unsigned)(lane % LPR) * 16u;   // byte slice in row
    const int ql = lane % LPR;
    const int DUMMY = (F == 128) ? N : 2 * N;   // both map to the zero row
    const char* Hb = (const char*)H;

    float acc[8];
#pragma unroll
    for (int f = 0; f < 8; ++f) acc[f] = 0.f;
    if (q == 0) {                        // self term H'[node]
        uint4 u = *(const uint4*)(Hb + (((unsigned)node << SH) + qb));
        acc[0] = bflo(u.x); acc[1] = bfhi(u.x);
        acc[2] = bflo(u.y); acc[3] = bfhi(u.y);
        acc[4] = bflo(u.z); acc[5] = bfhi(u.z);
        acc[6] = bflo(u.w); acc[7] = bfhi(u.w);
    }

#define GLD(s) (*(const uint4*)(Hb + (((unsigned)(s) << SH) + qb)))
#define ACC8(u)                                                         \
    acc[0] += bflo(u.x); acc[1] += bfhi(u.x);                           \
    acc[2] += bflo(u.y); acc[3] += bfhi(u.y);                           \
    acc[4] += bflo(u.z); acc[5] += bfhi(u.z);                           \
    acc[6] += bflo(u.w); acc[7] += bfhi(u.w);

    int start = row_ptr[node], end = row_ptr[node + 1];
    for (int base = start; base < end; base += 64) {
        int idx = DUMMY;
        if (base + lane < end) idx = col_idx[base + lane];
        int cnt = min(64, end - base);
        int j = 0;
        for (; j + 4 * EPW <= cnt; j += 4 * EPW) {
            int s0 = __shfl(idx, j + q);
            int s1 = __shfl(idx, j + EPW + q);
            int s2 = __shfl(idx, j + 2 * EPW + q);
            int s3 = __shfl(idx, j + 3 * EPW + q);
            uint4 u0 = GLD(s0);
            uint4 u1 = GLD(s1);
            uint4 u2 = GLD(s2);
            uint4 u3 = GLD(s3);
            ACC8(u0); ACC8(u1); ACC8(u2); ACC8(u3);
        }
        if (j + 2 * EPW <= cnt) {
            int s0 = __shfl(idx, j + q);
            int s1 = __shfl(idx, j + EPW + q);
            uint4 u0 = GLD(s0);
            uint4 u1 = GLD(s1);
            ACC8(u0); ACC8(u1);
            j += 2 * EPW;
        }
        for (; j < cnt; j += EPW) {
            int s = __shfl(idx, j + q);
            uint4 u = GLD(s);
            ACC8(u);
        }
    }
#undef ACC8
#undef GLD

    // combine slice partials across edge slots
#pragma unroll
    for (int f = 0; f < 8; ++f) {
        if constexpr (F == 64) acc[f] += __shfl_xor(acc[f], 8);
        acc[f] += __shfl_xor(acc[f], 16);
        acc[f] += __shfl_xor(acc[f], 32);
    }

    float dv = dinv[node];
    if constexpr (OUTBF16) {
        if (q == 0) {
            float4 b0 = *(const float4*)&bias[ql * 8];
            float4 b1 = *(const float4*)&bias[ql * 8 + 4];
            float y[8];
            y[0] = dv * acc[0] + b0.x; y[1] = dv * acc[1] + b0.y;
            y[2] = dv * acc[2] + b0.z; y[3] = dv * acc[3] + b0.w;
            y[4] = dv * acc[4] + b1.x; y[5] = dv * acc[5] + b1.y;
            y[6] = dv * acc[6] + b1.z; y[7] = dv * acc[7] + b1.w;
            uint4 o;
            unsigned* ow = (unsigned*)&o;
#pragma unroll
            for (int k = 0; k < 4; ++k) {
                float a0 = y[2 * k], a1 = y[2 * k + 1];
                if (RELU) { a0 = fmaxf(a0, 0.f); a1 = fmaxf(a1, 0.f); }
                ow[k] = (unsigned)f2bf(a0) | ((unsigned)f2bf(a1) << 16);
            }
            *((uint4*)((unsigned short*)Yv + (size_t)node * F) + ql) = o;
        }
    } else {
        if (q < 2) {
            int fb = ql * 8 + q * 4;
            float4 b = *(const float4*)&bias[fb];
            float4 o;
            o.x = dv * acc[q * 4 + 0] + b.x;
            o.y = dv * acc[q * 4 + 1] + b.y;
            o.z = dv * acc[q * 4 + 2] + b.z;
            o.w = dv * acc[q * 4 + 3] + b.w;
            if (RELU) {
                o.x = fmaxf(o.x, 0.f); o.y = fmaxf(o.y, 0.f);
                o.z = fmaxf(o.z, 0.f); o.w = fmaxf(o.w, 0.f);
            }
            *(float4*)((float*)Yv + (size_t)node * F + fb) = o;
        }
    }
}

extern "C" void kernel_launch(void* const* d_in, const int* in_sizes, int n_in,
                              void* d_out, int out_size, void* d_ws, size_t ws_size,
                              hipStream_t stream) {
    const float* x  = (const float*)d_in[0];
    const int* eidx = (const int*)d_in[1];
    const float* W0 = (const float*)d_in[2];
    const float* b0 = (const float*)d_in[3];
    const float* W1 = (const float*)d_in[4];
    const float* b1 = (const float*)d_in[5];
    const float* W2 = (const float*)d_in[6];
    const float* b2 = (const float*)d_in[7];
    float* out = (float*)d_out;

    const int N = in_sizes[0] / 128;
    const int E = in_sizes[1] / 2;
    const int* srcp = eidx;
    const int* dstp = eidx + E;

    const int NBIN   = (N + BINW - 1) / BINW;       // 391 for N=100000
    const int NCHUNK = (E + CE - 1) / CE;           // 391 for E=1.6M

    char* p = (char*)d_ws;
    auto take = [&](size_t bytes) {
        char* r = p;
        p += (bytes + 255) & ~(size_t)255;
        return r;
    };
    int*            cnt     = (int*)take((size_t)NCHUNK * NBIN * 4);
    int*            off_cb  = (int*)take((size_t)NCHUNK * NBIN * 4);
    int*            tot     = (int*)take((size_t)NBIN * 4);
    int*            bin_off = (int*)take((size_t)(NBIN + 1) * 4);
    unsigned int*   bpack   = (unsigned int*)take((size_t)E * 4);
    int*            row_ptr = (int*)take((size_t)(N + 1) * 4);
    float*          dinv    = (float*)take((size_t)N * 4);
    int*            col_idx = (int*)take((size_t)E * 4);
    unsigned short* hbuf    = (unsigned short*)take((size_t)(N + 1) * 128 * 2);
    unsigned short* ybuf    = (unsigned short*)take((size_t)N * 128 * 2);
    unsigned short* wt0     = (unsigned short*)take((size_t)2 * 16384 * 2);
    unsigned short* wt1     = (unsigned short*)take((size_t)2 * 16384 * 2);
    unsigned short* wt2     = (unsigned short*)take((size_t)2 * 8192 * 2);

    // ---- CSR build (no memsets, no global atomics) ----
    k_binhist<<<NCHUNK, 256, NBIN * 4, stream>>>(dstp, cnt, NBIN, E);
    k_prepw<<<160, 256, 0, stream>>>(W0, W1, W2, wt0, wt1, wt2);
    k_colscan<<<NBIN, 256, 0, stream>>>(cnt, off_cb, tot, NBIN, NCHUNK);
    k_binoff<<<1, 512, 0, stream>>>(tot, bin_off, row_ptr,
                                    hbuf + (size_t)N * 128, NBIN, N, E);
    k_binscatter<<<NCHUNK, 256, NBIN * 4, stream>>>(srcp, dstp, off_cb, bin_off,
                                                    bpack, NBIN, E);
    k_bincsr<<<NBIN, 256, 0, stream>>>(bpack, bin_off, row_ptr, dinv,
                                       col_idx, N);

    int gemm_grid = (N + 127) / 128;
    int agg_grid  = (N + 3) / 4;

    // layer 0: h' = dinv*(x@W0) ; y = bf16( relu(dinv*(sum h') + b0) )
    k_gemm_mfma<128, false><<<gemm_grid, 256, 0, stream>>>(x, wt0, dinv, hbuf, N);
    k_agg<128, true, true><<<agg_grid, 256, 0, stream>>>(hbuf, row_ptr, col_idx,
                                                         dinv, b0, ybuf, N);
    // layer 1 (bf16 A -> 2-MFMA GEMM)
    k_gemm_mfma<128, true><<<gemm_grid, 256, 0, stream>>>(ybuf, wt1, dinv, hbuf, N);
    k_agg<128, true, true><<<agg_grid, 256, 0, stream>>>(hbuf, row_ptr, col_idx,
                                                         dinv, b1, ybuf, N);
    // layer 2 (64-wide, no relu, f32 straight to d_out)
    k_gemm_mfma<64, true><<<gemm_grid, 256, 0, stream>>>(ybuf, wt2, dinv, hbuf, N);
    k_agg<64, false, false><<<agg_grid, 256, 0, stream>>>(hbuf, row_ptr, col_idx,
                                                          dinv, b2, out, N);
}